// Round 12
// baseline (79.224 us; speedup 1.0000x reference)
//
#include <hip/hip_runtime.h>
#include <hip/hip_bf16.h>
#include <stdint.h>

typedef float f32x4 __attribute__((ext_vector_type(4)));
typedef short s16x8 __attribute__((ext_vector_type(8)));
typedef int   i32x4 __attribute__((ext_vector_type(4)));
typedef _Float16 f16x4 __attribute__((ext_vector_type(4)));
typedef unsigned int u32;

#define NNODES 4096
#define INC    256
#define OUTF   256
#define NEG    0.2f
#define SJ     8
#define JL     512          // j per k_gat block (2 phases of 256)

__device__ __forceinline__ unsigned short f2bf(float f) {
  unsigned u = __float_as_uint(f);
  u += 0x7FFFu + ((u >> 16) & 1u);          // RNE
  return (unsigned short)(u >> 16);
}
__device__ __forceinline__ unsigned encf(float x) {
  unsigned u = __float_as_uint(x);
  return (u & 0x80000000u) ? ~u : (u | 0x80000000u);
}
__device__ __forceinline__ float decf(unsigned e) {
  unsigned u = (e & 0x80000000u) ? (e ^ 0x80000000u) : ~e;
  return __uint_as_float(u);
}

// ---------------------------------------------------------------------------
// Kernel A (round-11 verbatim, passing): h = x @ W (f32). Block = 64n x 64c,
// 256 thr, thread = 4n x 4c. Stage full x-slab + W-slab in LDS once (129KB),
// one barrier, barrier-free K=256 loop. Grid (4 hb, 64 nb). Epilogue: el/er
// logits, QS packed exp pair, atomicMax er-max, transpose -> bf16 hT store,
// granule gg (8 n) of each 64-n tile stored at gg ^ (c&7).
// ---------------------------------------------------------------------------
__global__ __launch_bounds__(256) void k_feat(
    const float* __restrict__ x, const float* __restrict__ W,
    const float* __restrict__ attl, const float* __restrict__ attr,
    unsigned short* __restrict__ hT, float* __restrict__ el_t,
    u32* __restrict__ QS, unsigned* __restrict__ M_enc)
{
  __shared__ float smbuf[33024];
  float* xs  = smbuf;            // [64 n][260]: 1KB data + 16B pad per row
  float* wsl = smbuf + 16640;    // [256 k][64 c]
  const int tid  = threadIdx.x;
  const int lane = tid & 63, wid = tid >> 6;
  const int hb = blockIdx.x, nb = blockIdx.y;
  const int n0 = nb * 64, c0 = hb * 64;
  const int ty = tid >> 4, tx = tid & 15;

#pragma unroll
  for (int q = 0; q < 16; ++q) {
    const int n = wid * 16 + q;
    __builtin_amdgcn_global_load_lds(x + (size_t)(n0 + n) * INC + lane * 4,
                                     xs + n * 260, 16, 0, 0);
  }
#pragma unroll
  for (int q = 0; q < 16; ++q) {
    const int kb = (wid * 16 + q) * 4;
    __builtin_amdgcn_global_load_lds(
        W + (size_t)(kb + (lane >> 4)) * OUTF + c0 + (lane & 15) * 4,
        wsl + kb * 64, 16, 0, 0);
  }
  __syncthreads();

  f32x4 acc[4];
#pragma unroll
  for (int r = 0; r < 4; ++r) acc[r] = (f32x4){0.f, 0.f, 0.f, 0.f};

#pragma unroll 4
  for (int k4 = 0; k4 < 64; ++k4) {
    f32x4 a[4], b[4];
#pragma unroll
    for (int r = 0; r < 4; ++r)
      a[r] = *(const f32x4*)(xs + (ty * 4 + r) * 260 + k4 * 4);
#pragma unroll
    for (int kk = 0; kk < 4; ++kk)
      b[kk] = *(const f32x4*)(wsl + (k4 * 4 + kk) * 64 + tx * 4);
#pragma unroll
    for (int r = 0; r < 4; ++r)
#pragma unroll
      for (int kk = 0; kk < 4; ++kk)
        acc[r] += a[r][kk] * b[kk];
  }

  f32x4 al = *(const f32x4*)(attl + c0 + tx * 4);
  f32x4 ar = *(const f32x4*)(attr + c0 + tx * 4);
  float pl[4], pr[4];
#pragma unroll
  for (int r = 0; r < 4; ++r) {
    pl[r] = acc[r][0] * al[0] + acc[r][1] * al[1] + acc[r][2] * al[2] + acc[r][3] * al[3];
    pr[r] = acc[r][0] * ar[0] + acc[r][1] * ar[1] + acc[r][2] * ar[2] + acc[r][3] * ar[3];
  }
#pragma unroll
  for (int m = 1; m < 16; m <<= 1) {
#pragma unroll
    for (int r = 0; r < 4; ++r) {
      pl[r] += __shfl_xor(pl[r], m, 64);
      pr[r] += __shfl_xor(pr[r], m, 64);
    }
  }
  if (tx == 0) {
#pragma unroll
    for (int r = 0; r < 4; ++r) {
      el_t[hb * NNODES + n0 + ty * 4 + r] = pl[r];
      float q = __expf(pr[r]);
      float s = __expf(NEG * pr[r]);
      QS[hb * NNODES + n0 + ty * 4 + r] = (u32)f2bf(q) | ((u32)f2bf(s) << 16);
    }
  }
  float mx = fmaxf(fmaxf(pr[0], pr[1]), fmaxf(pr[2], pr[3]));
  mx = fmaxf(mx, __shfl_xor(mx, 16, 64));
  mx = fmaxf(mx, __shfl_xor(mx, 32, 64));
  if (lane == 0) atomicMax(M_enc + hb, encf(mx));

  // transpose via LDS (reuse xs region) and store bf16 hT, 8-way swizzled
  __syncthreads();
  float* smT = smbuf;  // [64 c][65]
#pragma unroll
  for (int r = 0; r < 4; ++r)
#pragma unroll
    for (int j = 0; j < 4; ++j)
      smT[(tx * 4 + j) * 65 + ty * 4 + r] = acc[r][j];
  __syncthreads();
  {
    const int c = tid >> 2, g0 = tid & 3;
    const int key = c & 7;                 // (c0+c)&7 == c&7 (c0 mult of 64)
#pragma unroll
    for (int t = 0; t < 2; ++t) {
      const int gg = g0 + t * 4;           // granule of 8 n within 64-n tile
      unsigned v[4];
#pragma unroll
      for (int i = 0; i < 4; ++i) {
        unsigned lo = f2bf(smT[c * 65 + gg * 8 + 2 * i]);
        unsigned hi = f2bf(smT[c * 65 + gg * 8 + 2 * i + 1]);
        v[i] = lo | (hi << 16);
      }
      unsigned short* dst = hT + (size_t)(c0 + c) * NNODES + n0 + ((gg ^ key) * 8);
      *(uint4*)dst = make_uint4(v[0], v[1], v[2], v[3]);
    }
  }
}

// ---------------------------------------------------------------------------
// Kernel B: round-11 structure re-partitioned for TLP. Block = 1024 thr =
// 16 waves, ONE head per wave: h = wid&3, i-chunk ic = wid>>2 -> block =
// 64 i x 4 heads x 512 j. Same 128KB hbuf slab (2 phases of 256 j), same
// barrier pattern, same 3-bit swizzle pos formula, same writer. acc/wave
// drops 80->20 AGPR, arch regs ~halve -> under the 128-reg occupancy cliff
// -> 16 waves/CU = 4 waves/SIMD (was 2). Grid (64, 8).
// ---------------------------------------------------------------------------
__global__ __launch_bounds__(1024, 4) void k_gat(
    const int* __restrict__ adj, const unsigned short* __restrict__ hT,
    const float* __restrict__ el_t, const u32* __restrict__ QS,
    const unsigned* __restrict__ M_enc,
    _Float16* __restrict__ nump, float* __restrict__ denp)
{
  __shared__ __align__(16) unsigned short hbuf[256 * 256];  // 128KB [256 c][256 j]
  __shared__ __align__(16) u32 qsb[4 * JL];                 // 8KB [4 h][512 j]

  const int tid = threadIdx.x;
  const int wid = tid >> 6, lane = tid & 63;
  const int l15 = lane & 15, lg = lane >> 4;
  const int h  = wid & 3;
  const int ic = wid >> 2;
  const int i0 = blockIdx.x * 64;
  const int js = blockIdx.y;
  const int j0 = js * JL;
  const int irow = i0 + ic * 16 + l15;
  const int key = l15 & 7;

  const float el = el_t[h * NNODES + irow];
  const float M  = decf(M_enc[h]);
  const float sE = el + M;
  const float mih = fmaxf(sE, NEG * sE);   // >= every masked score for row i
  const float P = __expf(el - mih);
  const float R = __expf(NEG * el - mih);

  // QS staged once (both phases) by waves 0..7 (wave-uniform predicate)
  if (wid < 8)
    __builtin_amdgcn_global_load_lds(
        QS + (size_t)(wid >> 1) * NNODES + j0 + (wid & 1) * 256 + lane * 4,
        qsb + (wid >> 1) * JL + (wid & 1) * 256, 16, 0, 0);

  const int* asrc = adj + (size_t)irow * NNODES + j0 + lg * 8;

  f32x4 acc[4];
  f32x4 accd = (f32x4){0.f, 0.f, 0.f, 0.f};
#pragma unroll
  for (int c = 0; c < 4; ++c) acc[c] = (f32x4){0.f, 0.f, 0.f, 0.f};
  s16x8 ones;
#pragma unroll
  for (int e = 0; e < 8; ++e) ones[e] = (short)0x3F80;  // bf16 1.0

  // stage hT slab for phase p: 8 x 1KB instrs/wave (2 c-rows each),
  // 16 waves cover 256 rows x 256 j
#define STAGE(p)                                                                 \
  do {                                                                           \
    _Pragma("unroll")                                                            \
    for (int q = 0; q < 8; ++q) {                                                \
      const int c2 = wid * 16 + q * 2;                                           \
      __builtin_amdgcn_global_load_lds(                                          \
          hT + (size_t)(c2 + (lane >> 5)) * NNODES + j0 + (p) * 256 + (lane & 31) * 8, \
          hbuf + c2 * 256, 16, 0, 0);                                            \
    }                                                                            \
  } while (0)

  STAGE(0);

#pragma unroll
  for (int p = 0; p < 2; ++p) {
    if (p == 1) {
      __syncthreads();          // all phase-0 LDS reads done before overwrite
      STAGE(1);
    }
    // prefetch adj chunk 0 of this phase (overlaps staging latency)
    i32x4 a0 = *(const i32x4*)(asrc + p * 256);
    i32x4 a1 = *(const i32x4*)(asrc + p * 256 + 4);
    __syncthreads();            // slab + QS ready (vmcnt drain + barrier)

#pragma unroll
    for (int K = 0; K < 8; ++K) {
      const int nK = (K < 7) ? (K + 1) : 7;
      i32x4 na0 = *(const i32x4*)(asrc + p * 256 + nK * 32);
      i32x4 na1 = *(const i32x4*)(asrc + p * 256 + nK * 32 + 4);

      const int pos = (K >> 1) * 64 + ((((K & 1) * 4 + lg) ^ key) * 8);
      const unsigned short* lb = hbuf + (h * 64 + l15) * 256 + pos;
      s16x8 b0 = *(const s16x8*)(lb);
      s16x8 b1 = *(const s16x8*)(lb + 16 * 256);
      s16x8 b2 = *(const s16x8*)(lb + 32 * 256);
      s16x8 b3 = *(const s16x8*)(lb + 48 * 256);
      const u32* qrow = qsb + h * JL + p * 256 + K * 32 + lg * 8;
      i32x4 q0 = *(const i32x4*)(qrow);
      i32x4 q1 = *(const i32x4*)(qrow + 4);

      float w[8];
#pragma unroll
      for (int e = 0; e < 4; ++e) {
        u32 m0 = (a0[e] > 0) ? (u32)q0[e] : 0u;
        u32 m1 = (a1[e] > 0) ? (u32)q1[e] : 0u;
        float qq0 = __uint_as_float(m0 << 16);
        float ss0 = __uint_as_float(m0 & 0xffff0000u);
        float qq1 = __uint_as_float(m1 << 16);
        float ss1 = __uint_as_float(m1 & 0xffff0000u);
        w[e]     = fmaxf(P * qq0, R * ss0);
        w[e + 4] = fmaxf(P * qq1, R * ss1);
      }
      union { u32 uu[4]; s16x8 v; } af;
#pragma unroll
      for (int pp = 0; pp < 4; ++pp)
        asm("v_cvt_pk_bf16_f32 %0, %1, %2"
            : "=v"(af.uu[pp]) : "v"(w[2 * pp]), "v"(w[2 * pp + 1]));

      acc[0] = __builtin_amdgcn_mfma_f32_16x16x32_bf16(af.v, b0,   acc[0], 0, 0, 0);
      acc[1] = __builtin_amdgcn_mfma_f32_16x16x32_bf16(af.v, b1,   acc[1], 0, 0, 0);
      acc[2] = __builtin_amdgcn_mfma_f32_16x16x32_bf16(af.v, b2,   acc[2], 0, 0, 0);
      acc[3] = __builtin_amdgcn_mfma_f32_16x16x32_bf16(af.v, b3,   acc[3], 0, 0, 0);
      accd   = __builtin_amdgcn_mfma_f32_16x16x32_bf16(af.v, ones, accd,   0, 0, 0);

      a0 = na0; a1 = na1;
    }
  }
#undef STAGE

  // C/D layout: col = lane&15 (i), row = (lane>>4)*4 + reg
  const int orow = i0 + ic * 16 + lg * 4;
  _Float16* np = nump + ((size_t)js * NNODES + orow) * OUTF + h * 64 + l15;
#pragma unroll
  for (int c = 0; c < 4; ++c)
#pragma unroll
    for (int r = 0; r < 4; ++r)
      np[r * OUTF + c * 16] = (_Float16)acc[c][r];

  if (l15 == 0) {
    float* dp = denp + ((size_t)js * NNODES + orow) * 4 + h;
#pragma unroll
    for (int r = 0; r < 4; ++r) dp[r * 4] = accd[r];
  }
}

// ---------------------------------------------------------------------------
// Kernel C: sum f16 j-split partials, divide by den, add bias.
// ---------------------------------------------------------------------------
__global__ __launch_bounds__(256) void k_div(
    const _Float16* __restrict__ nump, const float* __restrict__ denp,
    const float* __restrict__ bias, float* __restrict__ out)
{
  const int q  = blockIdx.x * 256 + threadIdx.x;  // float4 index
  const int n  = q >> 6;
  const int c4 = (q & 63) * 4;
  const int h  = c4 >> 6;
  f32x4 s = {0.f, 0.f, 0.f, 0.f};
  float d = 0.f;
#pragma unroll
  for (int t = 0; t < SJ; ++t) {
    f16x4 v = *(const f16x4*)(nump + ((size_t)t * NNODES + n) * OUTF + c4);
    s[0] += (float)v[0]; s[1] += (float)v[1];
    s[2] += (float)v[2]; s[3] += (float)v[3];
    d += denp[((size_t)t * NNODES + n) * 4 + h];
  }
  f32x4 b = *(const f32x4*)(bias + c4);
  float r = __builtin_amdgcn_rcpf(d);
  f32x4 o = s * r + b;
  *(f32x4*)(out + (size_t)n * OUTF + c4) = o;
}

extern "C" void kernel_launch(void* const* d_in, const int* in_sizes, int n_in,
                              void* d_out, int out_size, void* d_ws, size_t ws_size,
                              hipStream_t stream)
{
  const float* x    = (const float*)d_in[0];
  const int*   adj  = (const int*)d_in[1];
  const float* W    = (const float*)d_in[2];
  const float* attl = (const float*)d_in[3];
  const float* attr = (const float*)d_in[4];
  const float* bias = (const float*)d_in[5];
  float* out = (float*)d_out;
  char*  ws  = (char*)d_ws;

  // workspace layout (~19MB)
  unsigned short* hT  = (unsigned short*)ws;                        // 2 MB
  float*     el_t  = (float*)(ws + (2u << 20));                     // 64 KB
  u32*       QS    = (u32*)(ws + (2u << 20) + (64u << 10));         // 64 KB
  unsigned*  M_enc = (unsigned*)(ws + (2u << 20) + (128u << 10));   // 16 B
  float*     denp  = (float*)(ws + (2u << 20) + (192u << 10));      // 512 KB
  _Float16*  nump  = (_Float16*)(ws + (3u << 20));                  // 16 MB

  hipMemsetAsync(M_enc, 0, 16, stream);
  k_feat<<<dim3(4, 64), 256, 0, stream>>>(x, W, attl, attr, hT, el_t, QS, M_enc);
  k_gat<<<dim3(64, SJ), 1024, 0, stream>>>(adj, hT, el_t, QS, M_enc, nump, denp);
  k_div<<<dim3(1024), 256, 0, stream>>>(nump, denp, bias, out);
}

// Round 13
// 62.485 us; speedup vs baseline: 1.2679x; 1.2679x over previous
//
#include <hip/hip_runtime.h>
#include <hip/hip_bf16.h>
#include <stdint.h>

typedef float f32x4 __attribute__((ext_vector_type(4)));
typedef short s16x8 __attribute__((ext_vector_type(8)));
typedef int   i32x4 __attribute__((ext_vector_type(4)));
typedef _Float16 f16x4 __attribute__((ext_vector_type(4)));
typedef unsigned int u32;

#define NNODES 4096
#define NEG    0.2f
#define SJ     8
#define JL     512
#define OUTF   256

__device__ __forceinline__ unsigned short f2bf(float f) {
  unsigned u = __float_as_uint(f);
  u += 0x7FFFu + ((u >> 16) & 1u);          // RNE
  return (unsigned short)(u >> 16);
}
__device__ __forceinline__ unsigned encf(float x) {
  unsigned u = __float_as_uint(x);
  return (u & 0x80000000u) ? ~u : (u | 0x80000000u);
}
__device__ __forceinline__ float decf(unsigned e) {
  unsigned u = (e & 0x80000000u) ? (e ^ 0x80000000u) : ~e;
  return __uint_as_float(u);
}

// ---------------------------------------------------------------------------
// k_prep: Wl/Wr[k][h] = sum_c W[k][h*64+c]*att{l,r}[h*64+c] (exact f32), and
// WT[c][k] = bf16(W[k][c]) transposed, granule (8 k) G of row c stored at
// (G&24)|((G&7)^(c&7)). Grid 32 x 256 thr; block = 8 k-rows. Barrier between
// cross-wave att_s/wt stores and reads (R9 fix).
// ---------------------------------------------------------------------------
__global__ __launch_bounds__(256) void k_prep(
    const float* __restrict__ W, const float* __restrict__ attl,
    const float* __restrict__ attr,
    unsigned short* __restrict__ WT, float* __restrict__ Wlr)
{
  __shared__ float wt[8 * 256];
  __shared__ float att_s[512];
  const int tid = threadIdx.x;
  const int kr = tid >> 5, l32 = tid & 31;
  const int k = blockIdx.x * 8 + kr;
  const float* wrow = W + (size_t)k * 256 + l32 * 8;
  f32x4 w0 = *(const f32x4*)(wrow);
  f32x4 w1 = *(const f32x4*)(wrow + 4);
  *(f32x4*)(wt + kr * 256 + l32 * 8)     = w0;
  *(f32x4*)(wt + kr * 256 + l32 * 8 + 4) = w1;
  att_s[tid]       = attl[tid];
  att_s[256 + tid] = attr[tid];
  __syncthreads();                          // att_s + wt visible to all waves

  float pl = 0.f, pr = 0.f;
#pragma unroll
  for (int i = 0; i < 4; ++i) {
    pl += w0[i] * att_s[l32 * 8 + i] + w1[i] * att_s[l32 * 8 + 4 + i];
    pr += w0[i] * att_s[256 + l32 * 8 + i] + w1[i] * att_s[256 + l32 * 8 + 4 + i];
  }
  pl += __shfl_xor(pl, 1, 64); pl += __shfl_xor(pl, 2, 64); pl += __shfl_xor(pl, 4, 64);
  pr += __shfl_xor(pr, 1, 64); pr += __shfl_xor(pr, 2, 64); pr += __shfl_xor(pr, 4, 64);
  if ((l32 & 7) == 0) {
    Wlr[k * 8 + (l32 >> 3)]     = pl;       // head g left weight
    Wlr[k * 8 + 4 + (l32 >> 3)] = pr;       // head g right weight
  }
  {
    const int c = tid;
    unsigned v[4];
#pragma unroll
    for (int i = 0; i < 4; ++i) {
      unsigned lo = f2bf(wt[(2 * i) * 256 + c]);
      unsigned hi = f2bf(wt[(2 * i + 1) * 256 + c]);
      v[i] = lo | (hi << 16);
    }
    const int gW = blockIdx.x;                       // k-granule in [0,32)
    const int pos = (gW & 24) | ((gW & 7) ^ (c & 7));
    *(uint4*)(WT + (size_t)c * 256 + pos * 8) = make_uint4(v[0], v[1], v[2], v[3]);
  }
}

// ---------------------------------------------------------------------------
// k_el: exact f32 logits el/er via x @ Wl / x @ Wr, QS packed
// (bf16 exp(er) | bf16 exp(0.2 er)<<16), atomicMax er-max per head, and
// xbf[n][k] = bf16(x), k-granule G of row n stored at (G&24)|((G&7)^(n&7)).
// Grid 256 x 256 thr; 16 lanes per node, shuffle-reduced.
// ---------------------------------------------------------------------------
__global__ __launch_bounds__(256) void k_el(
    const float* __restrict__ x, const float* __restrict__ Wlr,
    float* __restrict__ el_t, u32* __restrict__ QS,
    unsigned* __restrict__ M_enc, unsigned short* __restrict__ xbf)
{
  __shared__ float wls[16 * 145];  // [l15][i][9]: 8 data + 1 pad
  __shared__ float er_s[64];
  const int tid = threadIdx.x;
  {
    f32x4 a = *(const f32x4*)(Wlr + tid * 8);
    f32x4 b = *(const f32x4*)(Wlr + tid * 8 + 4);
    float* d = wls + (tid >> 4) * 145 + (tid & 15) * 9;
    *(f32x4*)d = a; *(f32x4*)(d + 4) = b;
  }
  __syncthreads();
  const int nl = tid >> 4, l15 = tid & 15;
  const int n = blockIdx.x * 16 + nl;
  f32x4 xv[4];
#pragma unroll
  for (int i = 0; i < 4; ++i)
    xv[i] = *(const f32x4*)(x + (size_t)n * 256 + l15 * 16 + i * 4);
  f32x4 al = {0.f,0.f,0.f,0.f}, ar = {0.f,0.f,0.f,0.f};
  const float* wb = wls + l15 * 145;
#pragma unroll
  for (int i = 0; i < 16; ++i) {
    float xi = xv[i >> 2][i & 3];
    f32x4 wl = *(const f32x4*)(wb + i * 9);
    f32x4 wr = *(const f32x4*)(wb + i * 9 + 4);
    al += xi * wl; ar += xi * wr;
  }
#pragma unroll
  for (int m = 1; m < 16; m <<= 1)
#pragma unroll
    for (int c = 0; c < 4; ++c) {
      al[c] += __shfl_xor(al[c], m, 64);
      ar[c] += __shfl_xor(ar[c], m, 64);
    }
  if (l15 == 0) {
#pragma unroll
    for (int h = 0; h < 4; ++h) {
      el_t[h * NNODES + n] = al[h];
      float q = __expf(ar[h]);
      float s = __expf(NEG * ar[h]);
      QS[h * NNODES + n] = (u32)f2bf(q) | ((u32)f2bf(s) << 16);
      er_s[nl * 4 + h] = ar[h];
    }
  }
  // xbf: pack 16 bf16 (k = l15*16..+15), two swizzled 16B stores
  {
    u32 pk[8];
#pragma unroll
    for (int i = 0; i < 8; ++i) {
      unsigned lo = f2bf(xv[(2 * i) >> 2][(2 * i) & 3]);
      unsigned hi = f2bf(xv[(2 * i + 1) >> 2][(2 * i + 1) & 3]);
      pk[i] = lo | (hi << 16);
    }
    const int key = n & 7;
    const int g0 = l15 * 2;
    const int p0 = (g0 & 24) | ((g0 & 7) ^ key);
    const int p1 = (g0 & 24) | (((g0 + 1) & 7) ^ key);
    unsigned short* xb = xbf + (size_t)n * 256;
    *(uint4*)(xb + p0 * 8) = make_uint4(pk[0], pk[1], pk[2], pk[3]);
    *(uint4*)(xb + p1 * 8) = make_uint4(pk[4], pk[5], pk[6], pk[7]);
  }
  __syncthreads();
  if (tid < 64) {
    float v = er_s[tid];
    v = fmaxf(v, __shfl_xor(v, 4, 64));
    v = fmaxf(v, __shfl_xor(v, 8, 64));
    v = fmaxf(v, __shfl_xor(v, 16, 64));
    v = fmaxf(v, __shfl_xor(v, 32, 64));
    if (tid < 4) atomicMax(M_enc + tid, encf(v));
  }
}

// ---------------------------------------------------------------------------
// k_hmm: hT[c][n] = bf16( sum_k W[k][c]*x[n][k] ) via mfma_16x16x32_bf16.
// A = WT rows (c), B = xbf rows (n), both LDS-staged linear and read with
// their 3-bit swizzle. D: row (lg,r) = c, col l15 = n. Output written with
// the 64-n-group swizzle (key c&7) that k_gat's reader expects.
// Block = 64c x 128n, 4 waves. Grid (4, 32).
// ---------------------------------------------------------------------------
__global__ __launch_bounds__(256) void k_hmm(
    const unsigned short* __restrict__ xbf, const unsigned short* __restrict__ WT,
    unsigned short* __restrict__ hT)
{
  __shared__ __align__(16) unsigned short xs[128 * 256];  // 64KB
  __shared__ __align__(16) unsigned short ws[64 * 256];   // 32KB
  const int tid = threadIdx.x, wv = tid >> 6, lane = tid & 63;
  const int l15 = lane & 15, lg = lane >> 4;
  const int c0 = blockIdx.x * 64, n0 = blockIdx.y * 128;
#pragma unroll
  for (int q = 0; q < 16; ++q) {
    const int r2 = (wv * 16 + q) * 2;
    __builtin_amdgcn_global_load_lds(
        xbf + (size_t)(n0 + r2 + (lane >> 5)) * 256 + (lane & 31) * 8,
        xs + r2 * 256, 16, 0, 0);
  }
#pragma unroll
  for (int q = 0; q < 8; ++q) {
    const int r2 = (wv * 8 + q) * 2;
    __builtin_amdgcn_global_load_lds(
        WT + (size_t)(c0 + r2 + (lane >> 5)) * 256 + (lane & 31) * 8,
        ws + r2 * 256, 16, 0, 0);
  }
  __syncthreads();
  f32x4 acc[8];
#pragma unroll
  for (int nt = 0; nt < 8; ++nt) acc[nt] = (f32x4){0.f,0.f,0.f,0.f};
  const int key = l15 & 7;
#pragma unroll
  for (int kk = 0; kk < 8; ++kk) {
    const int G = kk * 4 + lg;
    const int pos = (G & 24) | ((G & 7) ^ key);
    s16x8 a = *(const s16x8*)(ws + (wv * 16 + l15) * 256 + pos * 8);
#pragma unroll
    for (int nt = 0; nt < 8; ++nt) {
      s16x8 b = *(const s16x8*)(xs + (nt * 16 + l15) * 256 + pos * 8);
      acc[nt] = __builtin_amdgcn_mfma_f32_16x16x32_bf16(a, b, acc[nt], 0, 0, 0);
    }
  }
  // D: row = lg*4 + r (c), col = l15 (n). Store with k_gat's 64-n swizzle.
#pragma unroll
  for (int nt = 0; nt < 8; ++nt)
#pragma unroll
    for (int r = 0; r < 4; ++r) {
      const int c = c0 + wv * 16 + lg * 4 + r;
      const int nloc = nt * 16 + l15;
      const int gl = nloc >> 3;
      const int posn = (gl & 8) | ((gl & 7) ^ (c & 7));
      hT[(size_t)c * NNODES + n0 + posn * 8 + (nloc & 7)] = f2bf(acc[nt][r]);
    }
}

// ---------------------------------------------------------------------------
// k_gat (round-11 verbatim, passing, 43us): fused masked-softmax + PV.
// Block = 512 thr = 8 waves, each wave = 16 i-rows x ALL 4 heads. Block owns
// JL=512 j as 2 slabs of 256 j x 256 channels (128KB LDS), 4 barriers total.
// 3-bit swizzle pos = (K>>1)*64 + ((((K&1)*4+lg) ^ (l15&7))*8).
// ---------------------------------------------------------------------------
__global__ __launch_bounds__(512, 2) void k_gat(
    const int* __restrict__ adj, const unsigned short* __restrict__ hT,
    const float* __restrict__ el_t, const u32* __restrict__ QS,
    const unsigned* __restrict__ M_enc,
    _Float16* __restrict__ nump, float* __restrict__ denp)
{
  __shared__ __align__(16) unsigned short hbuf[256 * 256];  // 128KB [256 c][256 j]
  __shared__ __align__(16) u32 qsb[4 * JL];                 // 8KB [4 h][512 j]

  const int tid = threadIdx.x;
  const int wid = tid >> 6, lane = tid & 63;
  const int l15 = lane & 15, lg = lane >> 4;
  const int i0 = blockIdx.x * 128 + wid * 16;
  const int js = blockIdx.y;
  const int j0 = js * JL;
  const int key = l15 & 7;

  float P[4], R[4];
#pragma unroll
  for (int h = 0; h < 4; ++h) {
    float el  = el_t[h * NNODES + i0 + l15];
    float M   = decf(M_enc[h]);
    float sE  = el + M;
    float mih = fmaxf(sE, NEG * sE);   // >= every masked score for row i
    P[h] = __expf(el - mih);
    R[h] = __expf(NEG * el - mih);
  }

  // QS staged once (both phases): 8 waves x 1KB
  __builtin_amdgcn_global_load_lds(
      QS + (size_t)(wid >> 1) * NNODES + j0 + (wid & 1) * 256 + lane * 4,
      qsb + (wid >> 1) * JL + (wid & 1) * 256, 16, 0, 0);

  const int* asrc = adj + (size_t)(i0 + l15) * NNODES + j0 + lg * 8;

  f32x4 acc[4][4];
  f32x4 accd[4];
#pragma unroll
  for (int h = 0; h < 4; ++h) {
    accd[h] = (f32x4){0.f, 0.f, 0.f, 0.f};
#pragma unroll
    for (int c = 0; c < 4; ++c) acc[h][c] = (f32x4){0.f, 0.f, 0.f, 0.f};
  }
  s16x8 ones;
#pragma unroll
  for (int e = 0; e < 8; ++e) ones[e] = (short)0x3F80;  // bf16 1.0

#define STAGE(p)                                                                 \
  do {                                                                           \
    _Pragma("unroll")                                                            \
    for (int q = 0; q < 16; ++q) {                                               \
      const int c2 = wid * 32 + q * 2;                                           \
      __builtin_amdgcn_global_load_lds(                                          \
          hT + (size_t)(c2 + (lane >> 5)) * NNODES + j0 + (p) * 256 + (lane & 31) * 8, \
          hbuf + c2 * 256, 16, 0, 0);                                            \
    }                                                                            \
  } while (0)

  STAGE(0);

#pragma unroll
  for (int p = 0; p < 2; ++p) {
    if (p == 1) {
      __syncthreads();          // all phase-0 LDS reads done before overwrite
      STAGE(1);
    }
    i32x4 a0 = *(const i32x4*)(asrc + p * 256);
    i32x4 a1 = *(const i32x4*)(asrc + p * 256 + 4);
    __syncthreads();            // slab + QS ready

#pragma unroll
    for (int K = 0; K < 8; ++K) {
      const int nK = (K < 7) ? (K + 1) : 7;
      i32x4 na0 = *(const i32x4*)(asrc + p * 256 + nK * 32);
      i32x4 na1 = *(const i32x4*)(asrc + p * 256 + nK * 32 + 4);

      const int pos = (K >> 1) * 64 + ((((K & 1) * 4 + lg) ^ key) * 8);

#pragma unroll
      for (int h = 0; h < 4; ++h) {
        const unsigned short* lb = hbuf + (h * 64 + l15) * 256 + pos;
        s16x8 b0 = *(const s16x8*)(lb);
        s16x8 b1 = *(const s16x8*)(lb + 16 * 256);
        s16x8 b2 = *(const s16x8*)(lb + 32 * 256);
        s16x8 b3 = *(const s16x8*)(lb + 48 * 256);
        const u32* qrow = qsb + h * JL + p * 256 + K * 32 + lg * 8;
        i32x4 q0 = *(const i32x4*)(qrow);
        i32x4 q1 = *(const i32x4*)(qrow + 4);

        float w[8];
#pragma unroll
        for (int e = 0; e < 4; ++e) {
          u32 m0 = (a0[e] > 0) ? (u32)q0[e] : 0u;
          u32 m1 = (a1[e] > 0) ? (u32)q1[e] : 0u;
          float qq0 = __uint_as_float(m0 << 16);
          float ss0 = __uint_as_float(m0 & 0xffff0000u);
          float qq1 = __uint_as_float(m1 << 16);
          float ss1 = __uint_as_float(m1 & 0xffff0000u);
          w[e]     = fmaxf(P[h] * qq0, R[h] * ss0);
          w[e + 4] = fmaxf(P[h] * qq1, R[h] * ss1);
        }
        union { u32 uu[4]; s16x8 v; } af;
#pragma unroll
        for (int pp = 0; pp < 4; ++pp)
          asm("v_cvt_pk_bf16_f32 %0, %1, %2"
              : "=v"(af.uu[pp]) : "v"(w[2 * pp]), "v"(w[2 * pp + 1]));

        acc[h][0] = __builtin_amdgcn_mfma_f32_16x16x32_bf16(af.v, b0,   acc[h][0], 0, 0, 0);
        acc[h][1] = __builtin_amdgcn_mfma_f32_16x16x32_bf16(af.v, b1,   acc[h][1], 0, 0, 0);
        acc[h][2] = __builtin_amdgcn_mfma_f32_16x16x32_bf16(af.v, b2,   acc[h][2], 0, 0, 0);
        acc[h][3] = __builtin_amdgcn_mfma_f32_16x16x32_bf16(af.v, b3,   acc[h][3], 0, 0, 0);
        accd[h]   = __builtin_amdgcn_mfma_f32_16x16x32_bf16(af.v, ones, accd[h],   0, 0, 0);
      }
      a0 = na0; a1 = na1;
    }
  }
#undef STAGE

  // C/D layout: col = lane&15, row = (lane>>4)*4 + reg
  const int orow = i0 + lg * 4;
#pragma unroll
  for (int h = 0; h < 4; ++h) {
    _Float16* np = nump + ((size_t)js * NNODES + orow) * OUTF + h * 64 + l15;
#pragma unroll
    for (int c = 0; c < 4; ++c)
#pragma unroll
      for (int r = 0; r < 4; ++r)
        np[r * OUTF + c * 16] = (_Float16)acc[h][c][r];
  }
  if (l15 == 0) {
    float* dp = denp + ((size_t)js * NNODES + orow) * 4;
#pragma unroll
    for (int h = 0; h < 4; ++h)
#pragma unroll
      for (int r = 0; r < 4; ++r) dp[r * 4 + h] = accd[h][r];
  }
}

// ---------------------------------------------------------------------------
// k_div: sum f16 j-split partials, divide by den, add bias.
// ---------------------------------------------------------------------------
__global__ __launch_bounds__(256) void k_div(
    const _Float16* __restrict__ nump, const float* __restrict__ denp,
    const float* __restrict__ bias, float* __restrict__ out)
{
  const int q  = blockIdx.x * 256 + threadIdx.x;  // float4 index
  const int n  = q >> 6;
  const int c4 = (q & 63) * 4;
  const int h  = c4 >> 6;
  f32x4 s = {0.f, 0.f, 0.f, 0.f};
  float d = 0.f;
#pragma unroll
  for (int t = 0; t < SJ; ++t) {
    f16x4 v = *(const f16x4*)(nump + ((size_t)t * NNODES + n) * OUTF + c4);
    s[0] += (float)v[0]; s[1] += (float)v[1];
    s[2] += (float)v[2]; s[3] += (float)v[3];
    d += denp[((size_t)t * NNODES + n) * 4 + h];
  }
  f32x4 b = *(const f32x4*)(bias + c4);
  float r = __builtin_amdgcn_rcpf(d);
  f32x4 o = s * r + b;
  *(f32x4*)(out + (size_t)n * OUTF + c4) = o;
}

extern "C" void kernel_launch(void* const* d_in, const int* in_sizes, int n_in,
                              void* d_out, int out_size, void* d_ws, size_t ws_size,
                              hipStream_t stream)
{
  const float* x    = (const float*)d_in[0];
  const int*   adj  = (const int*)d_in[1];
  const float* W    = (const float*)d_in[2];
  const float* attl = (const float*)d_in[3];
  const float* attr = (const float*)d_in[4];
  const float* bias = (const float*)d_in[5];
  float* out = (float*)d_out;
  char*  ws  = (char*)d_ws;

  // workspace layout (19 MB; xbf aliases nump's js=7 slab — consumed by
  // k_hmm before k_gat writes it, stream-ordered)
  unsigned short* hT   = (unsigned short*)ws;                         // 2 MB
  float*     el_t  = (float*)(ws + (2u << 20));                       // 64 KB
  u32*       QS    = (u32*)(ws + (2u << 20) + (64u << 10));           // 64 KB
  unsigned*  M_enc = (unsigned*)(ws + (2u << 20) + (128u << 10));     // 16 B
  float*     denp  = (float*)(ws + (2u << 20) + (192u << 10));        // 512 KB
  unsigned short* WT = (unsigned short*)(ws + (2u << 20) + (704u << 10)); // 128 KB
  float*     Wlr   = (float*)(ws + (2u << 20) + (832u << 10));        // 8 KB
  _Float16*  nump  = (_Float16*)(ws + (3u << 20));                    // 16 MB
  unsigned short* xbf = (unsigned short*)(ws + (17u << 20));          // 2 MB (alias)

  hipMemsetAsync(M_enc, 0, 16, stream);
  k_prep<<<32, 256, 0, stream>>>(W, attl, attr, WT, Wlr);
  k_el<<<256, 256, 0, stream>>>(x, Wlr, el_t, QS, M_enc, xbf);
  k_hmm<<<dim3(4, 32), 256, 0, stream>>>(xbf, WT, hT);
  k_gat<<<dim3(32, SJ), 512, 0, stream>>>(adj, hT, el_t, QS, M_enc, nump, denp);
  k_div<<<1024, 256, 0, stream>>>(nump, denp, bias, out);
}

// Round 14
// 62.056 us; speedup vs baseline: 1.2767x; 1.0069x over previous
//
#include <hip/hip_runtime.h>
#include <hip/hip_bf16.h>
#include <stdint.h>

typedef float f32x4 __attribute__((ext_vector_type(4)));
typedef short s16x8 __attribute__((ext_vector_type(8)));
typedef int   i32x4 __attribute__((ext_vector_type(4)));
typedef _Float16 f16x4 __attribute__((ext_vector_type(4)));
typedef unsigned int u32;

#define NNODES 4096
#define NEG    0.2f
#define SJ     8
#define JL     512
#define OUTF   256

__device__ __forceinline__ unsigned short f2bf(float f) {
  unsigned u = __float_as_uint(f);
  u += 0x7FFFu + ((u >> 16) & 1u);          // RNE
  return (unsigned short)(u >> 16);
}
__device__ __forceinline__ unsigned encf(float x) {
  unsigned u = __float_as_uint(x);
  return (u & 0x80000000u) ? ~u : (u | 0x80000000u);
}
__device__ __forceinline__ float decf(unsigned e) {
  unsigned u = (e & 0x80000000u) ? (e ^ 0x80000000u) : ~e;
  return __uint_as_float(u);
}

// ---------------------------------------------------------------------------
// k_prep (R13 verbatim, passing): Wl/Wr[k][h] exact f32; WT[c][k] bf16
// transposed, k-granule G of row c at (G&24)|((G&7)^(c&7)).
// ---------------------------------------------------------------------------
__global__ __launch_bounds__(256) void k_prep(
    const float* __restrict__ W, const float* __restrict__ attl,
    const float* __restrict__ attr,
    unsigned short* __restrict__ WT, float* __restrict__ Wlr)
{
  __shared__ float wt[8 * 256];
  __shared__ float att_s[512];
  const int tid = threadIdx.x;
  const int kr = tid >> 5, l32 = tid & 31;
  const int k = blockIdx.x * 8 + kr;
  const float* wrow = W + (size_t)k * 256 + l32 * 8;
  f32x4 w0 = *(const f32x4*)(wrow);
  f32x4 w1 = *(const f32x4*)(wrow + 4);
  *(f32x4*)(wt + kr * 256 + l32 * 8)     = w0;
  *(f32x4*)(wt + kr * 256 + l32 * 8 + 4) = w1;
  att_s[tid]       = attl[tid];
  att_s[256 + tid] = attr[tid];
  __syncthreads();                          // att_s + wt visible to all waves

  float pl = 0.f, pr = 0.f;
#pragma unroll
  for (int i = 0; i < 4; ++i) {
    pl += w0[i] * att_s[l32 * 8 + i] + w1[i] * att_s[l32 * 8 + 4 + i];
    pr += w0[i] * att_s[256 + l32 * 8 + i] + w1[i] * att_s[256 + l32 * 8 + 4 + i];
  }
  pl += __shfl_xor(pl, 1, 64); pl += __shfl_xor(pl, 2, 64); pl += __shfl_xor(pl, 4, 64);
  pr += __shfl_xor(pr, 1, 64); pr += __shfl_xor(pr, 2, 64); pr += __shfl_xor(pr, 4, 64);
  if ((l32 & 7) == 0) {
    Wlr[k * 8 + (l32 >> 3)]     = pl;
    Wlr[k * 8 + 4 + (l32 >> 3)] = pr;
  }
  {
    const int c = tid;
    unsigned v[4];
#pragma unroll
    for (int i = 0; i < 4; ++i) {
      unsigned lo = f2bf(wt[(2 * i) * 256 + c]);
      unsigned hi = f2bf(wt[(2 * i + 1) * 256 + c]);
      v[i] = lo | (hi << 16);
    }
    const int gW = blockIdx.x;
    const int pos = (gW & 24) | ((gW & 7) ^ (c & 7));
    *(uint4*)(WT + (size_t)c * 256 + pos * 8) = make_uint4(v[0], v[1], v[2], v[3]);
  }
}

// ---------------------------------------------------------------------------
// k_el (R13 verbatim, passing): exact logits, QS pack, er-max, xbf bf16.
// ---------------------------------------------------------------------------
__global__ __launch_bounds__(256) void k_el(
    const float* __restrict__ x, const float* __restrict__ Wlr,
    float* __restrict__ el_t, u32* __restrict__ QS,
    unsigned* __restrict__ M_enc, unsigned short* __restrict__ xbf)
{
  __shared__ float wls[16 * 145];
  __shared__ float er_s[64];
  const int tid = threadIdx.x;
  {
    f32x4 a = *(const f32x4*)(Wlr + tid * 8);
    f32x4 b = *(const f32x4*)(Wlr + tid * 8 + 4);
    float* d = wls + (tid >> 4) * 145 + (tid & 15) * 9;
    *(f32x4*)d = a; *(f32x4*)(d + 4) = b;
  }
  __syncthreads();
  const int nl = tid >> 4, l15 = tid & 15;
  const int n = blockIdx.x * 16 + nl;
  f32x4 xv[4];
#pragma unroll
  for (int i = 0; i < 4; ++i)
    xv[i] = *(const f32x4*)(x + (size_t)n * 256 + l15 * 16 + i * 4);
  f32x4 al = {0.f,0.f,0.f,0.f}, ar = {0.f,0.f,0.f,0.f};
  const float* wb = wls + l15 * 145;
#pragma unroll
  for (int i = 0; i < 16; ++i) {
    float xi = xv[i >> 2][i & 3];
    f32x4 wl = *(const f32x4*)(wb + i * 9);
    f32x4 wr = *(const f32x4*)(wb + i * 9 + 4);
    al += xi * wl; ar += xi * wr;
  }
#pragma unroll
  for (int m = 1; m < 16; m <<= 1)
#pragma unroll
    for (int c = 0; c < 4; ++c) {
      al[c] += __shfl_xor(al[c], m, 64);
      ar[c] += __shfl_xor(ar[c], m, 64);
    }
  if (l15 == 0) {
#pragma unroll
    for (int h = 0; h < 4; ++h) {
      el_t[h * NNODES + n] = al[h];
      float q = __expf(ar[h]);
      float s = __expf(NEG * ar[h]);
      QS[h * NNODES + n] = (u32)f2bf(q) | ((u32)f2bf(s) << 16);
      er_s[nl * 4 + h] = ar[h];
    }
  }
  {
    u32 pk[8];
#pragma unroll
    for (int i = 0; i < 8; ++i) {
      unsigned lo = f2bf(xv[(2 * i) >> 2][(2 * i) & 3]);
      unsigned hi = f2bf(xv[(2 * i + 1) >> 2][(2 * i + 1) & 3]);
      pk[i] = lo | (hi << 16);
    }
    const int key = n & 7;
    const int g0 = l15 * 2;
    const int p0 = (g0 & 24) | ((g0 & 7) ^ key);
    const int p1 = (g0 & 24) | (((g0 + 1) & 7) ^ key);
    unsigned short* xb = xbf + (size_t)n * 256;
    *(uint4*)(xb + p0 * 8) = make_uint4(pk[0], pk[1], pk[2], pk[3]);
    *(uint4*)(xb + p1 * 8) = make_uint4(pk[4], pk[5], pk[6], pk[7]);
  }
  __syncthreads();
  if (tid < 64) {
    float v = er_s[tid];
    v = fmaxf(v, __shfl_xor(v, 4, 64));
    v = fmaxf(v, __shfl_xor(v, 8, 64));
    v = fmaxf(v, __shfl_xor(v, 16, 64));
    v = fmaxf(v, __shfl_xor(v, 32, 64));
    if (tid < 4) atomicMax(M_enc + tid, encf(v));
  }
}

// ---------------------------------------------------------------------------
// k_hmm (R13 verbatim, passing): hT = bf16(W^T x^T) via MFMA; output written
// with the 64-n-group swizzle (key c&7).
// ---------------------------------------------------------------------------
__global__ __launch_bounds__(256) void k_hmm(
    const unsigned short* __restrict__ xbf, const unsigned short* __restrict__ WT,
    unsigned short* __restrict__ hT)
{
  __shared__ __align__(16) unsigned short xs[128 * 256];
  __shared__ __align__(16) unsigned short ws[64 * 256];
  const int tid = threadIdx.x, wv = tid >> 6, lane = tid & 63;
  const int l15 = lane & 15, lg = lane >> 4;
  const int c0 = blockIdx.x * 64, n0 = blockIdx.y * 128;
#pragma unroll
  for (int q = 0; q < 16; ++q) {
    const int r2 = (wv * 16 + q) * 2;
    __builtin_amdgcn_global_load_lds(
        xbf + (size_t)(n0 + r2 + (lane >> 5)) * 256 + (lane & 31) * 8,
        xs + r2 * 256, 16, 0, 0);
  }
#pragma unroll
  for (int q = 0; q < 8; ++q) {
    const int r2 = (wv * 8 + q) * 2;
    __builtin_amdgcn_global_load_lds(
        WT + (size_t)(c0 + r2 + (lane >> 5)) * 256 + (lane & 31) * 8,
        ws + r2 * 256, 16, 0, 0);
  }
  __syncthreads();
  f32x4 acc[8];
#pragma unroll
  for (int nt = 0; nt < 8; ++nt) acc[nt] = (f32x4){0.f,0.f,0.f,0.f};
  const int key = l15 & 7;
#pragma unroll
  for (int kk = 0; kk < 8; ++kk) {
    const int G = kk * 4 + lg;
    const int pos = (G & 24) | ((G & 7) ^ key);
    s16x8 a = *(const s16x8*)(ws + (wv * 16 + l15) * 256 + pos * 8);
#pragma unroll
    for (int nt = 0; nt < 8; ++nt) {
      s16x8 b = *(const s16x8*)(xs + (nt * 16 + l15) * 256 + pos * 8);
      acc[nt] = __builtin_amdgcn_mfma_f32_16x16x32_bf16(a, b, acc[nt], 0, 0, 0);
    }
  }
#pragma unroll
  for (int nt = 0; nt < 8; ++nt)
#pragma unroll
    for (int r = 0; r < 4; ++r) {
      const int c = c0 + wv * 16 + lg * 4 + r;
      const int nloc = nt * 16 + l15;
      const int gl = nloc >> 3;
      const int posn = (gl & 8) | ((gl & 7) ^ (c & 7));
      hT[(size_t)c * NNODES + n0 + posn * 8 + (nloc & 7)] = f2bf(acc[nt][r]);
    }
}

// ---------------------------------------------------------------------------
// k_gat v14: R13's inner math verbatim, re-partitioned for occupancy.
// Block = 512 thr = 8 waves = 4 i-chunks x 2 head-groups; wave = 16 i x
// 2 heads (40 AGPR). Block = 64 i x 512 j. Slab = [256 c][128 j] = 64KB,
// 4 phases (+qsb 8KB) -> 72KB -> 2 blocks/CU; regs ~125 -> 3-4 waves/SIMD.
// Same swizzle algebra as R11/R13 (HW-verified family): slab offset
// G0 = K*4+lg in [0,16); pos = (G0&8)|((G0&7)^(l15&7)). Grid (64, 8).
// ---------------------------------------------------------------------------
__global__ __launch_bounds__(512, 3) void k_gat(
    const int* __restrict__ adj, const unsigned short* __restrict__ hT,
    const float* __restrict__ el_t, const u32* __restrict__ QS,
    const unsigned* __restrict__ M_enc,
    _Float16* __restrict__ nump, float* __restrict__ denp)
{
  __shared__ __align__(16) unsigned short hbuf[256 * 128];  // 64KB [256 c][128 j]
  __shared__ __align__(16) u32 qsb[4 * JL];                 // 8KB [4 h][512 j]

  const int tid = threadIdx.x;
  const int wid = tid >> 6, lane = tid & 63;
  const int l15 = lane & 15, lg = lane >> 4;
  const int ic = wid & 3, hg = wid >> 2;   // 4 i-chunks x 2 head-groups
  const int i0 = blockIdx.x * 64;
  const int js = blockIdx.y;
  const int j0 = js * JL;
  const int irow = i0 + ic * 16 + l15;
  const int key = l15 & 7;

  float P[2], R[2];
#pragma unroll
  for (int hh = 0; hh < 2; ++hh) {
    const int h = hg * 2 + hh;
    float el  = el_t[h * NNODES + irow];
    float M   = decf(M_enc[h]);
    float sE  = el + M;
    float mih = fmaxf(sE, NEG * sE);   // >= every masked score for row i
    P[hh] = __expf(el - mih);
    R[hh] = __expf(NEG * el - mih);
  }

  // QS staged once (all 4 phases): 8 waves x 1KB
  __builtin_amdgcn_global_load_lds(
      QS + (size_t)(wid >> 1) * NNODES + j0 + (wid & 1) * 256 + lane * 4,
      qsb + (wid >> 1) * JL + (wid & 1) * 256, 16, 0, 0);

  const int* asrc = adj + (size_t)irow * NNODES + j0 + lg * 8;

  f32x4 acc[2][4];
  f32x4 accd[2];
#pragma unroll
  for (int hh = 0; hh < 2; ++hh) {
    accd[hh] = (f32x4){0.f, 0.f, 0.f, 0.f};
#pragma unroll
    for (int c = 0; c < 4; ++c) acc[hh][c] = (f32x4){0.f, 0.f, 0.f, 0.f};
  }
  s16x8 ones;
#pragma unroll
  for (int e = 0; e < 8; ++e) ones[e] = (short)0x3F80;  // bf16 1.0

  // stage slab for phase p: 8 x 1KB instrs/wave (4 rows x 128 j each)
#define STAGE(p)                                                                 \
  do {                                                                           \
    _Pragma("unroll")                                                            \
    for (int q = 0; q < 8; ++q) {                                                \
      const int r4 = (wid * 8 + q) * 4;                                          \
      __builtin_amdgcn_global_load_lds(                                          \
          hT + (size_t)(r4 + (lane >> 4)) * NNODES + j0 + (p) * 128 + (lane & 15) * 8, \
          hbuf + r4 * 128, 16, 0, 0);                                            \
    }                                                                            \
  } while (0)

  STAGE(0);
  // prefetch adj chunk 0 (overlaps staging latency)
  i32x4 a0 = *(const i32x4*)(asrc);
  i32x4 a1 = *(const i32x4*)(asrc + 4);

#pragma unroll
  for (int p = 0; p < 4; ++p) {
    if (p) {
      __syncthreads();          // phase p-1 LDS reads done before overwrite
      STAGE(p);
    }
    __syncthreads();            // slab (+QS) ready: vmcnt drained by barrier

#pragma unroll
    for (int K = 0; K < 4; ++K) {
      const int t = p * 4 + K;
      const int tn = (t < 15) ? t + 1 : t;
      i32x4 na0 = *(const i32x4*)(asrc + tn * 32);
      i32x4 na1 = *(const i32x4*)(asrc + tn * 32 + 4);

      const int G0 = K * 4 + lg;                        // [0,16)
      const int pos = (G0 & 8) | ((G0 & 7) ^ key);

#pragma unroll
      for (int hh = 0; hh < 2; ++hh) {
        const int h = hg * 2 + hh;
        const unsigned short* lb = hbuf + (h * 64 + l15) * 128 + pos * 8;
        s16x8 b0 = *(const s16x8*)(lb);
        s16x8 b1 = *(const s16x8*)(lb + 16 * 128);
        s16x8 b2 = *(const s16x8*)(lb + 32 * 128);
        s16x8 b3 = *(const s16x8*)(lb + 48 * 128);
        const u32* qrow = qsb + h * JL + t * 32 + lg * 8;
        i32x4 q0 = *(const i32x4*)(qrow);
        i32x4 q1 = *(const i32x4*)(qrow + 4);

        float w[8];
#pragma unroll
        for (int e = 0; e < 4; ++e) {
          u32 m0 = (a0[e] > 0) ? (u32)q0[e] : 0u;
          u32 m1 = (a1[e] > 0) ? (u32)q1[e] : 0u;
          float qq0 = __uint_as_float(m0 << 16);
          float ss0 = __uint_as_float(m0 & 0xffff0000u);
          float qq1 = __uint_as_float(m1 << 16);
          float ss1 = __uint_as_float(m1 & 0xffff0000u);
          w[e]     = fmaxf(P[hh] * qq0, R[hh] * ss0);
          w[e + 4] = fmaxf(P[hh] * qq1, R[hh] * ss1);
        }
        union { u32 uu[4]; s16x8 v; } af;
#pragma unroll
        for (int pp = 0; pp < 4; ++pp)
          asm("v_cvt_pk_bf16_f32 %0, %1, %2"
              : "=v"(af.uu[pp]) : "v"(w[2 * pp]), "v"(w[2 * pp + 1]));

        acc[hh][0] = __builtin_amdgcn_mfma_f32_16x16x32_bf16(af.v, b0,   acc[hh][0], 0, 0, 0);
        acc[hh][1] = __builtin_amdgcn_mfma_f32_16x16x32_bf16(af.v, b1,   acc[hh][1], 0, 0, 0);
        acc[hh][2] = __builtin_amdgcn_mfma_f32_16x16x32_bf16(af.v, b2,   acc[hh][2], 0, 0, 0);
        acc[hh][3] = __builtin_amdgcn_mfma_f32_16x16x32_bf16(af.v, b3,   acc[hh][3], 0, 0, 0);
        accd[hh]   = __builtin_amdgcn_mfma_f32_16x16x32_bf16(af.v, ones, accd[hh],   0, 0, 0);
      }
      a0 = na0; a1 = na1;
    }
  }
#undef STAGE

  // C/D layout: col = lane&15 (i), row = (lane>>4)*4 + reg
  const int orow = i0 + ic * 16 + lg * 4;
#pragma unroll
  for (int hh = 0; hh < 2; ++hh) {
    const int h = hg * 2 + hh;
    _Float16* np = nump + ((size_t)js * NNODES + orow) * OUTF + h * 64 + l15;
#pragma unroll
    for (int c = 0; c < 4; ++c)
#pragma unroll
      for (int r = 0; r < 4; ++r)
        np[r * OUTF + c * 16] = (_Float16)acc[hh][c][r];
  }
  if (l15 == 0) {
    float* dp = denp + ((size_t)js * NNODES + orow) * 4;
#pragma unroll
    for (int hh = 0; hh < 2; ++hh)
#pragma unroll
      for (int r = 0; r < 4; ++r) dp[r * 4 + hg * 2 + hh] = accd[hh][r];
  }
}

// ---------------------------------------------------------------------------
// k_div (R13 verbatim): sum f16 j-split partials, divide by den, add bias.
// ---------------------------------------------------------------------------
__global__ __launch_bounds__(256) void k_div(
    const _Float16* __restrict__ nump, const float* __restrict__ denp,
    const float* __restrict__ bias, float* __restrict__ out)
{
  const int q  = blockIdx.x * 256 + threadIdx.x;
  const int n  = q >> 6;
  const int c4 = (q & 63) * 4;
  const int h  = c4 >> 6;
  f32x4 s = {0.f, 0.f, 0.f, 0.f};
  float d = 0.f;
#pragma unroll
  for (int t = 0; t < SJ; ++t) {
    f16x4 v = *(const f16x4*)(nump + ((size_t)t * NNODES + n) * OUTF + c4);
    s[0] += (float)v[0]; s[1] += (float)v[1];
    s[2] += (float)v[2]; s[3] += (float)v[3];
    d += denp[((size_t)t * NNODES + n) * 4 + h];
  }
  f32x4 b = *(const f32x4*)(bias + c4);
  float r = __builtin_amdgcn_rcpf(d);
  f32x4 o = s * r + b;
  *(f32x4*)(out + (size_t)n * OUTF + c4) = o;
}

extern "C" void kernel_launch(void* const* d_in, const int* in_sizes, int n_in,
                              void* d_out, int out_size, void* d_ws, size_t ws_size,
                              hipStream_t stream)
{
  const float* x    = (const float*)d_in[0];
  const int*   adj  = (const int*)d_in[1];
  const float* W    = (const float*)d_in[2];
  const float* attl = (const float*)d_in[3];
  const float* attr = (const float*)d_in[4];
  const float* bias = (const float*)d_in[5];
  float* out = (float*)d_out;
  char*  ws  = (char*)d_ws;

  // workspace layout (19 MB; xbf aliases nump's js=7 slab — consumed by
  // k_hmm before k_gat writes it, stream-ordered)
  unsigned short* hT   = (unsigned short*)ws;                         // 2 MB
  float*     el_t  = (float*)(ws + (2u << 20));                       // 64 KB
  u32*       QS    = (u32*)(ws + (2u << 20) + (64u << 10));           // 64 KB
  unsigned*  M_enc = (unsigned*)(ws + (2u << 20) + (128u << 10));     // 16 B
  float*     denp  = (float*)(ws + (2u << 20) + (192u << 10));        // 512 KB
  unsigned short* WT = (unsigned short*)(ws + (2u << 20) + (704u << 10)); // 128 KB
  float*     Wlr   = (float*)(ws + (2u << 20) + (832u << 10));        // 8 KB
  _Float16*  nump  = (_Float16*)(ws + (3u << 20));                    // 16 MB
  unsigned short* xbf = (unsigned short*)(ws + (17u << 20));          // 2 MB (alias)

  hipMemsetAsync(M_enc, 0, 16, stream);
  k_prep<<<32, 256, 0, stream>>>(W, attl, attr, WT, Wlr);
  k_el<<<256, 256, 0, stream>>>(x, Wlr, el_t, QS, M_enc, xbf);
  k_hmm<<<dim3(4, 32), 256, 0, stream>>>(xbf, WT, hT);
  k_gat<<<dim3(64, SJ), 512, 0, stream>>>(adj, hT, el_t, QS, M_enc, nump, denp);
  k_div<<<1024, 256, 0, stream>>>(nump, denp, bias, out);
}